// Round 1
// baseline (5066.500 us; speedup 1.0000x reference)
//
#include <hip/hip_runtime.h>
#include <stdint.h>

#define NB 4
#define NL 1024
#define NV 50257
#define ND 512
#define NVP 50304   // 393 * 128 (Wo padded rows)
#define NC 16       // recurrence workgroups (row-slices of Wh)

typedef __attribute__((ext_vector_type(8))) short short8;   // 8 bf16 = 4 VGPRs
typedef __attribute__((ext_vector_type(4))) float f32x4;

__device__ __forceinline__ unsigned short f2bf(float f) {
  __bf16 b = (__bf16)f;
  return __builtin_bit_cast(unsigned short, b);
}

__device__ __forceinline__ void gld_lds16(const void* g, void* l) {
  __builtin_amdgcn_global_load_lds(
      reinterpret_cast<const __attribute__((address_space(1))) void*>(
          reinterpret_cast<uintptr_t>(g)),
      reinterpret_cast<__attribute__((address_space(3))) void*>(
          reinterpret_cast<uintptr_t>(l)),
      16, 0, 0);
}

// ---------------- prep: Wo fp32 -> bf16 padded to NVP rows; bo padded -------
__global__ void k_prep(const float* __restrict__ Wo, const float* __restrict__ bo,
                       unsigned short* __restrict__ WoB, float* __restrict__ boP) {
  int gid = blockIdx.x * 256 + threadIdx.x;           // 12576*256 = NVP*ND/8
  size_t base = (size_t)gid * 8;                      // element index in [NVP][ND]
  int row = (int)(base >> 9);
  unsigned short ov[8];
  if (row < NV) {
    const float* src = Wo + (size_t)row * ND + (base & 511);
#pragma unroll
    for (int i = 0; i < 8; ++i) ov[i] = f2bf(src[i]);
  } else {
#pragma unroll
    for (int i = 0; i < 8; ++i) ov[i] = 0;
  }
  *(uint4*)(WoB + base) = *(uint4*)ov;
  if (gid < NVP) boP[gid] = (gid < NV) ? bo[gid] : 0.f;
}

// ---------------- transpose Wx [e][d] -> WxT [d][e] (for coalesced xproj) ---
__global__ void k_transpose(const float* __restrict__ Wx, float* __restrict__ WxT) {
  __shared__ float tile[32][33];
  int bx = blockIdx.x & 15, by = blockIdx.x >> 4;
  int tx = threadIdx.x & 31, ty = threadIdx.x >> 5;   // 256 threads, ty 0..7
#pragma unroll
  for (int i = 0; i < 32; i += 8)
    tile[ty + i][tx] = Wx[(size_t)(by * 32 + ty + i) * ND + bx * 32 + tx];
  __syncthreads();
#pragma unroll
  for (int i = 0; i < 32; i += 8)
    WxT[(size_t)(bx * 32 + ty + i) * ND + by * 32 + tx] = tile[tx][ty + i];
}

// ---------------- xproj[t][b][d] = emb[seq] @ Wx^T + bx  (fp32 exact) -------
__global__ void __launch_bounds__(256) k_xproj(
    const int* __restrict__ seq, const float* __restrict__ emb,
    const float* __restrict__ WxT, const float* __restrict__ bx,
    float* __restrict__ xproj) {
  __shared__ __align__(16) float xs[16][ND];          // 32 KB
  int b = blockIdx.x >> 6;
  int t0 = (blockIdx.x & 63) << 4;
  int tid = threadIdx.x;
#pragma unroll 1
  for (int rr = 0; rr < 16; ++rr) {
    int tok = seq[b * NL + t0 + rr];
    float2 v = *(const float2*)&emb[(size_t)tok * ND + tid * 2];
    *(float2*)&xs[rr][tid * 2] = v;
  }
  __syncthreads();
  int e0 = tid, e1 = tid + 256;
  float acc0[16], acc1[16];
#pragma unroll
  for (int rr = 0; rr < 16; ++rr) { acc0[rr] = 0.f; acc1[rr] = 0.f; }
  for (int d = 0; d < ND; d += 2) {
    float w00 = WxT[(size_t)d * ND + e0];
    float w01 = WxT[(size_t)d * ND + e1];
    float w10 = WxT[(size_t)(d + 1) * ND + e0];
    float w11 = WxT[(size_t)(d + 1) * ND + e1];
#pragma unroll
    for (int rr = 0; rr < 16; ++rr) {
      float2 xv = *(const float2*)&xs[rr][d];
      acc0[rr] += w00 * xv.x; acc0[rr] += w10 * xv.y;
      acc1[rr] += w01 * xv.x; acc1[rr] += w11 * xv.y;
    }
  }
  float b0 = bx[e0], b1 = bx[e1];
#pragma unroll
  for (int rr = 0; rr < 16; ++rr) {
    size_t rowb = (size_t)((t0 + rr) * NB + b) * ND;
    xproj[rowb + e0] = acc0[rr] + b0;
    xproj[rowb + e1] = acc1[rr] + b1;
  }
}

// ---------------- recurrence: NC WGs, Wh slice in registers, fp32 VALU ------
// thread(tid): w=tid/64, lane=tid%64, kc=lane&15 (k-chunk), nq=lane>>4,
// n = w*4+nq in [0,32) -> global row n0+n. Each thread holds Wh[n][kc*32..+31].
// h in LDS swizzled: hsw[slot=j*16+kc][b] holds h[b][k=kc*32+j] -> the float4
// read per j is bank-conflict-free (2-way alias only) and gives all 4 batches.
__global__ void __launch_bounds__(512) k_recur(
    const float* __restrict__ Wh, const float* __restrict__ bh,
    const float* __restrict__ xproj, float* __restrict__ hx,
    unsigned short* __restrict__ hs16, unsigned int* __restrict__ ctr) {
  __shared__ __align__(16) float hsw[ND * NB];        // 8 KB
  const int wg = blockIdx.x;
  const int n0 = wg * 32;
  const int tid = threadIdx.x;
  const int w = tid >> 6;
  const int lane = tid & 63;
  const int kc = lane & 15;
  const int nq = lane >> 4;
  const int n = w * 4 + nq;
  float wh[32];
  {
    const float* src = Wh + (size_t)(n0 + n) * ND + kc * 32;
#pragma unroll
    for (int j = 0; j < 32; j += 4) {
      float4 v = *(const float4*)(src + j);
      wh[j] = v.x; wh[j + 1] = v.y; wh[j + 2] = v.z; wh[j + 3] = v.w;
    }
  }
  const float bhn = bh[n0 + n];
  *(f32x4*)&hsw[tid * 4] = (f32x4){0.f, 0.f, 0.f, 0.f};   // h_{-1} = 0
  __syncthreads();

  for (int t = 0; t < NL; ++t) {
    float xp0 = 0.f, xp1 = 0.f, xp2 = 0.f, xp3 = 0.f;
    if (kc == 0) {                                   // prefetch, latency hidden
      const float* xb = xproj + (size_t)t * NB * ND + n0 + n;
      xp0 = xb[0]; xp1 = xb[ND]; xp2 = xb[2 * ND]; xp3 = xb[3 * ND];
    }
    float a0 = 0.f, a1 = 0.f, a2 = 0.f, a3 = 0.f;
#pragma unroll
    for (int j = 0; j < 32; ++j) {
      f32x4 hv = *(const f32x4*)&hsw[(j * 16 + kc) * 4];
      float wv = wh[j];
      a0 += wv * hv.x; a1 += wv * hv.y; a2 += wv * hv.z; a3 += wv * hv.w;
    }
#pragma unroll
    for (int off = 1; off < 16; off <<= 1) {          // reduce over kc
      a0 += __shfl_xor(a0, off, 64);
      a1 += __shfl_xor(a1, off, 64);
      a2 += __shfl_xor(a2, off, 64);
      a3 += __shfl_xor(a3, off, 64);
    }
    if (kc == 0) {
      float v0 = fmaxf(a0 + bhn + xp0, 0.f);
      float v1 = fmaxf(a1 + bhn + xp1, 0.f);
      float v2 = fmaxf(a2 + bhn + xp2, 0.f);
      float v3 = fmaxf(a3 + bhn + xp3, 0.f);
      float* hb = hx + (size_t)t * NB * ND + n0 + n;  // device-coherent exchange
      __hip_atomic_store(hb,          v0, __ATOMIC_RELAXED, __HIP_MEMORY_SCOPE_AGENT);
      __hip_atomic_store(hb + ND,     v1, __ATOMIC_RELAXED, __HIP_MEMORY_SCOPE_AGENT);
      __hip_atomic_store(hb + 2 * ND, v2, __ATOMIC_RELAXED, __HIP_MEMORY_SCOPE_AGENT);
      __hip_atomic_store(hb + 3 * ND, v3, __ATOMIC_RELAXED, __HIP_MEMORY_SCOPE_AGENT);
      const int col = n0 + n;                         // bf16 copy for the GEMM
      hs16[(size_t)(0 * NL + t) * ND + col] = f2bf(v0);
      hs16[(size_t)(1 * NL + t) * ND + col] = f2bf(v1);
      hs16[(size_t)(2 * NL + t) * ND + col] = f2bf(v2);
      hs16[(size_t)(3 * NL + t) * ND + col] = f2bf(v3);
    }
    asm volatile("s_waitcnt vmcnt(0)" ::: "memory");  // defensive: stores done
    __syncthreads();                                  // drains vmcnt before barrier
    if (tid == 0)
      __hip_atomic_fetch_add(&ctr[t], 1u, __ATOMIC_RELAXED, __HIP_MEMORY_SCOPE_AGENT);
    if (t == NL - 1) break;
    if (tid == 0) {
      while (__hip_atomic_load(&ctr[t], __ATOMIC_RELAXED, __HIP_MEMORY_SCOPE_AGENT) < NC) {}
    }
    __syncthreads();
    {
      const int slot = tid;                           // refill hsw with h_t
      const int k = (slot & 15) * 32 + (slot >> 4);
      const float* hb = hx + (size_t)t * NB * ND + k;
      f32x4 hv;
      hv.x = __hip_atomic_load(hb,          __ATOMIC_RELAXED, __HIP_MEMORY_SCOPE_AGENT);
      hv.y = __hip_atomic_load(hb + ND,     __ATOMIC_RELAXED, __HIP_MEMORY_SCOPE_AGENT);
      hv.z = __hip_atomic_load(hb + 2 * ND, __ATOMIC_RELAXED, __HIP_MEMORY_SCOPE_AGENT);
      hv.w = __hip_atomic_load(hb + 3 * ND, __ATOMIC_RELAXED, __HIP_MEMORY_SCOPE_AGENT);
      *(f32x4*)&hsw[slot * 4] = hv;
    }
    __syncthreads();
  }
}

// ---------------- out = hs @ Wo^T + bo   (m97-style bf16 MFMA GEMM) ---------
__global__ void __launch_bounds__(256) k_gemm(
    const unsigned short* __restrict__ A,   // hs16 [4096][512]
    const unsigned short* __restrict__ Bm,  // WoB  [NVP][512]
    const float* __restrict__ boP, float* __restrict__ out) {
  __shared__ __align__(16) unsigned short As[128 * 64];   // 16 KB
  __shared__ __align__(16) unsigned short Bs[128 * 64];   // 16 KB
  const int bid = blockIdx.x;
  const int mt = bid & 31;            // 32 consecutive blocks share the Wo tile
  const int nt = bid >> 5;
  const size_t m0 = (size_t)mt << 7;
  const size_t n0 = (size_t)nt << 7;
  const int tid = threadIdx.x;
  const int w = tid >> 6, lane = tid & 63;
  const int lm = lane & 15, q = lane >> 4;
  const int wm = (w & 1) << 6, wn = (w >> 1) << 6;
  f32x4 acc[4][4];
#pragma unroll
  for (int mi = 0; mi < 4; ++mi)
#pragma unroll
    for (int ni = 0; ni < 4; ++ni) acc[mi][ni] = (f32x4){0.f, 0.f, 0.f, 0.f};
  const int r = tid >> 3, c8 = (tid & 7) << 3;
  for (int kt = 0; kt < 8; ++kt) {
    const int k0 = kt << 6;
#pragma unroll
    for (int j = 0; j < 4; ++j) {
      const int row = j * 32 + r;
      gld_lds16(A  + (m0 + row) * ND + k0 + c8, &As[row * 64 + c8]);
      gld_lds16(Bm + (n0 + row) * ND + k0 + c8, &Bs[row * 64 + c8]);
    }
    __syncthreads();
#pragma unroll
    for (int ks = 0; ks < 2; ++ks) {
      short8 af[4], bfr[4];
#pragma unroll
      for (int mi = 0; mi < 4; ++mi)
        af[mi] = *(const short8*)&As[(wm + mi * 16 + lm) * 64 + ks * 32 + q * 8];
#pragma unroll
      for (int ni = 0; ni < 4; ++ni)
        bfr[ni] = *(const short8*)&Bs[(wn + ni * 16 + lm) * 64 + ks * 32 + q * 8];
#pragma unroll
      for (int mi = 0; mi < 4; ++mi)
#pragma unroll
        for (int ni = 0; ni < 4; ++ni)
          acc[mi][ni] = __builtin_amdgcn_mfma_f32_16x16x32_bf16(
              af[mi], bfr[ni], acc[mi][ni], 0, 0, 0);
    }
    __syncthreads();
  }
#pragma unroll
  for (int ni = 0; ni < 4; ++ni) {
    const size_t v = n0 + wn + ni * 16 + lm;
    if (v >= NV) continue;
    const float bov = boP[v];
#pragma unroll
    for (int mi = 0; mi < 4; ++mi) {
      const size_t mrow = m0 + wm + mi * 16 + q * 4;
#pragma unroll
      for (int rg = 0; rg < 4; ++rg)
        out[(mrow + rg) * (size_t)NV + v] = acc[mi][ni][rg] + bov;
    }
  }
}

extern "C" void kernel_launch(void* const* d_in, const int* in_sizes, int n_in,
                              void* d_out, int out_size, void* d_ws, size_t ws_size,
                              hipStream_t stream) {
  const int*   seq = (const int*)d_in[0];
  const float* emb = (const float*)d_in[1];
  const float* Wh  = (const float*)d_in[2];
  const float* bh  = (const float*)d_in[3];
  const float* Wx  = (const float*)d_in[4];
  const float* bx  = (const float*)d_in[5];
  const float* Wo  = (const float*)d_in[6];
  const float* bo  = (const float*)d_in[7];
  float* out = (float*)d_out;
  char* ws = (char*)d_ws;
  // workspace layout (all 16B aligned), total ~70.3 MB
  unsigned short* WoB  = (unsigned short*)(ws + 0);         // 51,511,296 B
  float*          boP  = (float*)(ws + 51511296);           //    201,216 B
  float*          WxT  = (float*)(ws + 51712512);           //  1,048,576 B
  float*          xprj = (float*)(ws + 52761088);           //  8,388,608 B
  float*          hx   = (float*)(ws + 61149696);           //  8,388,608 B
  unsigned short* hs16 = (unsigned short*)(ws + 69538304);  //  4,194,304 B
  unsigned int*   ctr  = (unsigned int*)(ws + 73732608);    //      4,096 B

  hipMemsetAsync(ctr, 0, NL * sizeof(unsigned int), stream);
  k_prep<<<dim3(12576), dim3(256), 0, stream>>>(Wo, bo, WoB, boP);
  k_transpose<<<dim3(256), dim3(256), 0, stream>>>(Wx, WxT);
  k_xproj<<<dim3(256), dim3(256), 0, stream>>>(seq, emb, WxT, bx, xprj);
  k_recur<<<dim3(NC), dim3(512), 0, stream>>>(Wh, bh, xprj, hx, hs16, ctr);
  k_gemm<<<dim3(12576), dim3(256), 0, stream>>>(hs16, WoB, boP, out);
}